// Round 5
// baseline (187.300 us; speedup 1.0000x reference)
//
#include <hip/hip_runtime.h>
#include <hip/hip_bf16.h>
#include <math.h>
#include <string.h>

// BilateralNet round 10: 2-output-tile waves -> halve LDS B-fragment traffic.
// Round-9 post-mortem: VGPR stuck at 84 under waves_per_eu(3,3) + PINV; no
// scratch in FETCH/WRITE; mlp improved only when PINV forced one-time cvt
// (r8). Conclusion: frags live in the AGPR half of the unified file (rocprof
// VGPR_Count = arch VGPRs only; MFMA reads A from AGPR natively). Allocator
// is fine. The REAL roof is the LDS pipe: 92 ds_read_b128/item/wave x 4
// waves x 37.5 items/CU x 12cyc = ~69us of a 95us kernel (~84% busy), because
// all 4 waves read IDENTICAL B fragments (each covers all 64px for 16 outs).
// Fix: wave (ow=w&1, pw=w>>1) computes o-tiles {2ow,2ow+1} for px-half pw:
// each B read feeds 2 MFMAs -> dense reads 80->40/item/wave; w6 reshaped to
// 5 real K-chunks/wave (12->10 reads, no zero-pad tiles). A-frags double to
// ~180 regs -> waves_per_eu(2,2) (256 budget), grid 512 = exactly 2
// blocks/CU (384x19 + 128x18 items).

#define NN   160
#define NPIX 25600   // 160*160

typedef __attribute__((ext_vector_type(4))) float float4v;
typedef __attribute__((ext_vector_type(8))) unsigned short ushort8;
typedef __attribute__((ext_vector_type(2))) unsigned int uint2v;
typedef __attribute__((ext_vector_type(4))) unsigned int uint4v;
typedef __attribute__((ext_vector_type(8))) __bf16 bf16x8;

// opaque read-write: forces one-time materialization of the converted value
#define PINV(x) asm volatile("" : "+v"(x))

__device__ __forceinline__ int refp(int a) { return (a <= NN - 1) ? a : (2 * (NN - 1) - a); }

__device__ __forceinline__ unsigned int pk2(float lo, float hi) {
    float2 f; f.x = lo; f.y = hi;
    __hip_bfloat162 h = __float22bfloat162_rn(f);   // v_cvt_pk_bf16_f32
    unsigned int u;
    memcpy(&u, &h, 4);
    return u;
}
__device__ __forceinline__ ushort8 cvt8(const float* __restrict__ p) {
    const float4v f0 = *(const float4v*)p;
    const float4v f1 = *(const float4v*)(p + 4);
    uint4v u;
    u[0] = pk2(f0[0], f0[1]); u[1] = pk2(f0[2], f0[3]);
    u[2] = pk2(f1[0], f1[1]); u[3] = pk2(f1[2], f1[3]);
    return __builtin_bit_cast(ushort8, u);
}

// one dense layer, 2-o-tile form: wave (ow,pw) computes outputs
// [ (2ow)*16 .. (2ow+2)*16 ) for pixels [ pw*32 .. pw*32+32 ).
// Reads X[0..K) once per (px-group, k-chunk); each read feeds 2 MFMAs.
template <int NCH>  // K = NCH*32 input channels
__device__ __forceinline__ void dense_layer2(const ushort8 (&A)[2][NCH],
                                             const float* __restrict__ bL,
                                             unsigned short* Xs,
                                             int ow, int pw, int lo16, int lq) {
    const int K = NCH * 32;
    const float4v bv0 = *(const float4v*)&bL[(2 * ow + 0) * 16 + lq * 4];
    const float4v bv1 = *(const float4v*)&bL[(2 * ow + 1) * 16 + lq * 4];
#pragma unroll
    for (int gi = 0; gi < 2; ++gi) {
        const int px = (2 * pw + gi) * 16 + lo16;
        float4v acc0 = bv0, acc1 = bv1;
#pragma unroll
        for (int s = 0; s < NCH; ++s) {
            const bf16x8 bf = __builtin_bit_cast(
                bf16x8, *(const ushort8*)&Xs[(s * 4 + lq) * 512 + px * 8]);
            acc0 = __builtin_amdgcn_mfma_f32_16x16x32_bf16(
                __builtin_bit_cast(bf16x8, A[0][s]), bf, acc0, 0, 0, 0);
            acc1 = __builtin_amdgcn_mfma_f32_16x16x32_bf16(
                __builtin_bit_cast(bf16x8, A[1][s]), bf, acc1, 0, 0, 0);
        }
        const int cb0 = K + (2 * ow) * 16 + lq * 4;   // (cb0&7)==(lq*4)&7
        const int cb1 = cb0 + 16;
        uint2v o0, o1;
        o0[0] = pk2(fmaxf(acc0[0], 0.0f), fmaxf(acc0[1], 0.0f));
        o0[1] = pk2(fmaxf(acc0[2], 0.0f), fmaxf(acc0[3], 0.0f));
        o1[0] = pk2(fmaxf(acc1[0], 0.0f), fmaxf(acc1[1], 0.0f));
        o1[1] = pk2(fmaxf(acc1[2], 0.0f), fmaxf(acc1[3], 0.0f));
        *(uint2v*)&Xs[(cb0 >> 3) * 512 + px * 8 + (cb0 & 7)] = o0;
        *(uint2v*)&Xs[(cb1 >> 3) * 512 + px * 8 + (cb1 & 7)] = o1;
    }
    __syncthreads();
}

__global__
__attribute__((amdgpu_flat_work_group_size(256, 256)))
__attribute__((amdgpu_waves_per_eu(2, 2)))
void bnet_mlp_kernel(
    const float* __restrict__ x,
    const float* __restrict__ wx, const float* __restrict__ bx,
    const float* __restrict__ wcs, const float* __restrict__ bcs,
    const float* __restrict__ wc, const float* __restrict__ bc,
    const float* __restrict__ w2, const float* __restrict__ b2,
    const float* __restrict__ w3, const float* __restrict__ b3,
    const float* __restrict__ w4, const float* __restrict__ b4,
    const float* __restrict__ w5, const float* __restrict__ b5,
    const float* __restrict__ w6,
    float* __restrict__ par)  // par[ch][b][pix], ch-major; pre-zeroed
{
    __shared__ unsigned short Xs[20480];    // 40 chunks x 1024 B = 40 KB exactly
    float* red = (float*)Xs;                // 2 KB aliased into chunks 0-1 (dead at flush)

    const int t = threadIdx.x;
    const int lane = t & 63;
    const int lo16 = lane & 15;
    const int lq = lane >> 4;
    const int w = __builtin_amdgcn_readfirstlane(t >> 6);  // wave id 0..3
    const int ow = w & 1;    // o-half: o-tiles {2ow, 2ow+1}
    const int pw = w >> 1;   // px-half: groups {2pw, 2pw+1}

    // ---- stage A-fragments ONCE per block (fp32 -> bf16 inline) ----
    ushort8 a2[2][2], a3[2][4], a4[2][6], a5[2][8], a6[5];
#pragma unroll
    for (int ot = 0; ot < 2; ++ot) {
        const int arow = (2 * ow + ot) * 16 + lo16;
#pragma unroll
        for (int s = 0; s < 2; ++s) { a2[ot][s] = cvt8(&w2[arow * 64 + s * 32 + lq * 8]);  PINV(a2[ot][s]); }
#pragma unroll
        for (int s = 0; s < 4; ++s) { a3[ot][s] = cvt8(&w3[arow * 128 + s * 32 + lq * 8]); PINV(a3[ot][s]); }
#pragma unroll
        for (int s = 0; s < 6; ++s) { a4[ot][s] = cvt8(&w4[arow * 192 + s * 32 + lq * 8]); PINV(a4[ot][s]); }
#pragma unroll
        for (int s = 0; s < 8; ++s) { a5[ot][s] = cvt8(&w5[arow * 256 + s * 32 + lq * 8]); PINV(a5[ot][s]); }
    }
    // w6 is 4x320 (padded to 16 rows). Waves sharing pw split the 10 K-chunks:
    // ow=0 -> chunks 0..4, ow=1 -> chunks 5..9. All chunks are real (no pad).
#pragma unroll
    for (int c = 0; c < 5; ++c) {
        const int ch = (ow * 5 + c) * 32;
        if (lo16 < 4) {
            a6[c] = cvt8(&w6[lo16 * 320 + ch + lq * 8]);
        } else {
            ushort8 z = {0, 0, 0, 0, 0, 0, 0, 0};
            a6[c] = z;
        }
        PINV(a6[c]);
    }

    // ---- item chunk: 9600 items over 512 blocks -> 384 x19 + 128 x18 ----
    const int bid = blockIdx.x;
    const int nit = 18 + (bid < 384 ? 1 : 0);
    const int g0  = (bid < 384) ? bid * 19 : bid * 18 + 384;

    // w6 partial accumulator: 2 px-groups x 4 outputs; persists across the
    // 12 (mode,rot) variants of a (tile,b) item group.
    float4v acc6[2];
    int cur_tb = -1;

    for (int it = 0; it < nit; ++it) {
        const int g = g0 + it;            // g = (tile*2+b)*12 + (mode*4+k)
        const int v = g % 12;
        const int tb = g / 12;
        const int tile = tb >> 1;
        const int b = tb & 1;
        const int mode = v >> 2;          // 0='x', 1='s', 2='c'
        const int k = v & 3;              // rotation

        __syncthreads();  // prior item's w6 reads of Xs done; Xs/red reusable

        if (tb != cur_tb) {               // block-uniform condition
            if (cur_tb >= 0) {
                // ---- flush prev tb: 2 ow-partials per pixel, wave 0 sums ----
                const int ftile = cur_tb >> 1;
                const int fb = cur_tb & 1;
                if (lq == 0) {
#pragma unroll
                    for (int gi = 0; gi < 2; ++gi)
                        *(float4v*)&red[(ow * 64 + (2 * pw + gi) * 16 + lo16) * 4] = acc6[gi];
                }
                __syncthreads();
                if (w == 0) {
                    float4v sv;
#pragma unroll
                    for (int r = 0; r < 4; ++r)
                        sv[r] = red[(lane) * 4 + r] + red[(64 + lane) * 4 + r];
                    const int pixg = ftile * 64 + lane;
#pragma unroll
                    for (int r = 0; r < 4; ++r)
                        atomicAdd(&par[(r * 2 + fb) * NPIX + pixg], sv[r]);  // b6 folded into kernel 2
                }
                __syncthreads();  // wave 0 done with red before conv overwrites chunks 0-1
            }
#pragma unroll
            for (int gi = 0; gi < 2; ++gi) { float4v z = {0.f, 0.f, 0.f, 0.f}; acc6[gi] = z; }
            cur_tb = tb;
        }

        const float* xb = x + b * NPIX;
        const float* w1 = (mode == 0) ? wx : (mode == 1) ? wcs : wc;
        const float* b1 = (mode == 0) ? bx : (mode == 1) ? bcs : bc;
        int DY[4], DX[4];
        if (mode == 0)      { DY[0]=0; DY[1]=0; DY[2]=1; DY[3]=1;  DX[0]=0; DX[1]=1; DX[2]=0; DX[3]=1; }
        else if (mode == 1) { DY[0]=0; DY[1]=1; DY[2]=1; DY[3]=2;  DX[0]=0; DX[1]=1; DX[2]=2; DX[3]=1; }
        else                { DY[0]=0; DY[1]=0; DY[2]=2; DY[3]=2;  DX[0]=0; DX[1]=2; DX[2]=0; DX[3]=2; }

        const int pix = tile * 64 + lane;
        const int pi = pix / NN;
        const int pj = pix - pi * NN;

        // ---- stage 1: 4-tap conv; thread owns ch w*16..+15 at px=lane ----
        float s4[4];
#pragma unroll
        for (int tt = 0; tt < 4; ++tt) {
            const int dy = DY[tt], dx = DX[tt];
            int r, c;
            if (k == 0)      { r = refp(pi + dy); c = refp(pj + dx); }
            else if (k == 1) { r = refp(pi + dx); c = (pj >= dy) ? (pj - dy) : (dy - pj); }
            else if (k == 2) { r = (pi >= dy) ? (pi - dy) : (dy - pi);
                               c = (pj >= dx) ? (pj - dx) : (dx - pj); }
            else             { r = (pi >= dx) ? (pi - dx) : (dx - pi); c = refp(pj + dy); }
            s4[tt] = xb[r * NN + c];
        }
        float4v b1v[4];
#pragma unroll
        for (int q = 0; q < 4; ++q) b1v[q] = *(const float4v*)&b1[w * 16 + q * 4];
        float co[16];
#pragma unroll
        for (int oo = 0; oo < 16; ++oo) {
            const int o = w * 16 + oo;
            const float4v wv = *(const float4v*)&w1[o * 4];
            float cacc = b1v[oo >> 2][oo & 3];
#pragma unroll
            for (int tt = 0; tt < 4; ++tt) cacc = fmaf(wv[tt], s4[tt], cacc);
            co[oo] = fmaxf(cacc, 0.0f);
        }
        uint4v pka, pkb;
#pragma unroll
        for (int q = 0; q < 4; ++q) {
            pka[q] = pk2(co[2 * q], co[2 * q + 1]);
            pkb[q] = pk2(co[8 + 2 * q], co[9 + 2 * q]);
        }
        *(uint4v*)&Xs[(w * 2) * 512 + lane * 8]     = pka;
        *(uint4v*)&Xs[(w * 2 + 1) * 512 + lane * 8] = pkb;
        __syncthreads();

        dense_layer2<2>(a2, b2, Xs, ow, pw, lo16, lq);
        dense_layer2<4>(a3, b3, Xs, ow, pw, lo16, lq);
        dense_layer2<6>(a4, b4, Xs, ow, pw, lo16, lq);
        dense_layer2<8>(a5, b5, Xs, ow, pw, lo16, lq);

        // ---- final layer partials: wave covers px-half pw, K-chunks 5ow..5ow+4 ----
        // accumulated across all variants of this tb (rotations folded into
        // the conv input addressing)
#pragma unroll
        for (int gi = 0; gi < 2; ++gi) {
            const int px = (2 * pw + gi) * 16 + lo16;
#pragma unroll
            for (int c = 0; c < 5; ++c) {
                const int c8 = (ow * 5 + c) * 4 + lq;
                const bf16x8 bf = __builtin_bit_cast(
                    bf16x8, *(const ushort8*)&Xs[c8 * 512 + px * 8]);
                acc6[gi] = __builtin_amdgcn_mfma_f32_16x16x32_bf16(
                    __builtin_bit_cast(bf16x8, a6[c]), bf, acc6[gi], 0, 0, 0);
            }
        }
        // loop-top __syncthreads() protects Xs reuse across items
    }

    // ---- final flush of the last tb ----
    __syncthreads();   // all w6 reads of Xs complete before red aliases it
    {
        const int ftile = cur_tb >> 1;
        const int fb = cur_tb & 1;
        if (lq == 0) {
#pragma unroll
            for (int gi = 0; gi < 2; ++gi)
                *(float4v*)&red[(ow * 64 + (2 * pw + gi) * 16 + lo16) * 4] = acc6[gi];
        }
        __syncthreads();
        if (w == 0) {
            float4v sv;
#pragma unroll
            for (int r = 0; r < 4; ++r)
                sv[r] = red[(lane) * 4 + r] + red[(64 + lane) * 4 + r];
            const int pixg = ftile * 64 + lane;
#pragma unroll
            for (int r = 0; r < 4; ++r)
                atomicAdd(&par[(r * 2 + fb) * NPIX + pixg], sv[r]);  // b6 folded into kernel 2
        }
    }
}

__global__ __launch_bounds__(64) void bnet_bilateral_kernel(
    const float* __restrict__ x, const float* __restrict__ b6,
    float* __restrict__ out)
{
    const int tid = blockIdx.x * 64 + threadIdx.x;  // 800 blocks x 64 = 51200 exactly
    const int b = tid / NPIX;
    const int pix = tid - b * NPIX;
    const int pi = pix / NN;
    const int pj = pix - pi * NN;

    float* par = out + 2 * NPIX;
    const float inv12 = 1.0f / 12.0f;
    const float p0 = par[(0 + b) * NPIX + pix] * inv12 + b6[0];
    const float p1 = par[(2 + b) * NPIX + pix] * inv12 + b6[1];
    const float p2 = par[(4 + b) * NPIX + pix] * inv12 + b6[2];
    const float p3 = par[(6 + b) * NPIX + pix] * inv12 + b6[3];

    float sigx = 1.0f / (1.0f + __expf(-p0)) + 1e-6f;
    sigx = fminf(fmaxf(sigx, 0.0f), 1.0f);
    float sigy = 1.0f / (1.0f + __expf(-p1)) + 1e-6f;
    sigy = fminf(fmaxf(sigy, 0.0f), 1.0f);
    float t2 = __expf(2.0f * fminf(fmaxf(p2, -15.0f), 15.0f));
    float th = (t2 - 1.0f) / (t2 + 1.0f);
    th = fminf(fmaxf(th, -1.0f), 1.0f);
    float t3 = __expf(2.0f * fminf(fmaxf(p3, -15.0f), 15.0f));
    float sigr = (t3 - 1.0f) / (t3 + 1.0f) + 1e-6f;
    sigr = fminf(fmaxf(sigr, -1.0f), 1.0f);

    par[(0 + b) * NPIX + pix] = sigx;
    par[(2 + b) * NPIX + pix] = sigy;
    par[(4 + b) * NPIX + pix] = th;
    par[(6 + b) * NPIX + pix] = sigr;

    const float sx = sigx * 20.0f;
    const float sy = sigy * 20.0f;
    const float sr = sigr * 10.0f + 10.0f;

    const float* xb = x + b * NPIX;
    float patch[5][5];
#pragma unroll
    for (int ky = 0; ky < 5; ++ky) {
#pragma unroll
        for (int kx = 0; kx < 5; ++kx) {
            const int r = pi + ky - 2, c = pj + kx - 2;
            patch[ky][kx] = (r >= 0 && r < NN && c >= 0 && c < NN) ? xb[r * NN + c] : 0.0f;
        }
    }

    const float inv2sr2 = 1.0f / (2.0f * sr * sr);
    float num = 0.0f, den = 0.0f;
#pragma unroll
    for (int ky = 0; ky < 5; ++ky) {
#pragma unroll
        for (int kx = 0; kx < 5; ++kx) {
            const float v = patch[ky][kx];
            const float dxv = fabsf(patch[2][kx] - v);
            const float dyv = fabsf(patch[ky][2] - v);
            const float a = sx * dxv;
            const float bb = sy * dyv;
            const float sq = (float)((ky - 2) * (ky - 2) + (kx - 2) * (kx - 2));
            const float kern = __expf(-sq * inv2sr2 - 0.5f * (a * a - 2.0f * th * a * bb + bb * bb));
            den += kern;
            num = fmaf(kern, v, num);
        }
    }
    out[tid] = num / den;
}

extern "C" void kernel_launch(void* const* d_in, const int* in_sizes, int n_in,
                              void* d_out, int out_size, void* d_ws, size_t ws_size,
                              hipStream_t stream) {
    const float* x   = (const float*)d_in[0];
    const float* wx  = (const float*)d_in[1];
    const float* bx  = (const float*)d_in[2];
    const float* wc  = (const float*)d_in[3];
    const float* bc  = (const float*)d_in[4];
    const float* wcs = (const float*)d_in[5];
    const float* bcs = (const float*)d_in[6];
    const float* w2  = (const float*)d_in[7];
    const float* b2  = (const float*)d_in[8];
    const float* w3  = (const float*)d_in[9];
    const float* b3  = (const float*)d_in[10];
    const float* w4  = (const float*)d_in[11];
    const float* b4  = (const float*)d_in[12];
    const float* w5  = (const float*)d_in[13];
    const float* b5  = (const float*)d_in[14];
    const float* w6  = (const float*)d_in[15];
    const float* b6  = (const float*)d_in[16];
    float* out = (float*)d_out;

    // zero the par accumulator region (d_out tail, re-poisoned each launch)
    (void)hipMemsetAsync(out + 2 * NPIX, 0, 8 * NPIX * sizeof(float), stream);

    hipLaunchKernelGGL(bnet_mlp_kernel, dim3(512), dim3(256), 0, stream,
                       x, wx, bx, wcs, bcs, wc, bc,
                       w2, b2, w3, b3, w4, b4, w5, b5, w6,
                       out + 2 * NPIX);

    hipLaunchKernelGGL(bnet_bilateral_kernel, dim3(800), dim3(64), 0, stream,
                       x, b6, out);
}

// Round 6
// 184.266 us; speedup vs baseline: 1.0165x; 1.0165x over previous
//
#include <hip/hip_runtime.h>
#include <hip/hip_bf16.h>
#include <math.h>
#include <string.h>

// BilateralNet round 11: stream pre-converted bf16 A-fragments from L2
// instead of persisting them in registers.
// Round-10 post-mortem: total VALU cycles and MFMA cycles were IDENTICAL
// r9 vs r10 (42.8/43.2 and 23.8/22.8 us-eq) -> halving ds_reads changed
// nothing; only occupancy fell (28.6->20.2%) -> kernel is latency-bound and
// REGISTER-footprint-bound (unified VGPR+AGPR: 180-reg A-set invisible to
// rocprof's arch-VGPR count forced 2 waves/SIMD).
// Fix: weights are 92 KB shared read-only across 256 CUs = L2-resident
// operand. A prep kernel converts fp32->bf16 once per launch into d_ws in
// exact fragment order; dense layers load A-frags per use (1 dwordx4 each,
// transient <=32 regs). Persistent state ~ acc6 only -> ~110 regs peak ->
// amdgpu_waves_per_eu(4,4), grid 1024 = 4 blocks/CU (160 KB LDS exact).
// L2 A-traffic ~12 TB/s aggregate < 34.5 TB/s ceiling.

#define NN   160
#define NPIX 25600   // 160*160

// ws layout (16B ushort8 units): dense frag(layer,s,row,lq) at
// OFF_l + (s*64+row)*4 + lq ; w6 frag(c,row16,lq) at 5120 + (c*16+row)*4+lq
#define W2OFF 0
#define W3OFF 512
#define W4OFF 1536
#define W5OFF 3072
#define W6OFF 5120
#define WSUNITS 5888   // 23 blocks x 256 threads

typedef __attribute__((ext_vector_type(4))) float float4v;
typedef __attribute__((ext_vector_type(8))) unsigned short ushort8;
typedef __attribute__((ext_vector_type(2))) unsigned int uint2v;
typedef __attribute__((ext_vector_type(4))) unsigned int uint4v;
typedef __attribute__((ext_vector_type(8))) __bf16 bf16x8;

__device__ __forceinline__ int refp(int a) { return (a <= NN - 1) ? a : (2 * (NN - 1) - a); }

__device__ __forceinline__ unsigned int pk2(float lo, float hi) {
    float2 f; f.x = lo; f.y = hi;
    __hip_bfloat162 h = __float22bfloat162_rn(f);   // v_cvt_pk_bf16_f32
    unsigned int u;
    memcpy(&u, &h, 4);
    return u;
}

// ---- prep: fp32 weights -> bf16 fragments in d_ws (frag-order layout) ----
__global__ __launch_bounds__(256) void bnet_prep_kernel(
    const float* __restrict__ w2, const float* __restrict__ w3,
    const float* __restrict__ w4, const float* __restrict__ w5,
    const float* __restrict__ w6, ushort8* __restrict__ ws)
{
    const int u = blockIdx.x * 256 + threadIdx.x;   // 0..5887
    const int lq = u & 3;
    float src[8];
    if (u < W6OFF) {
        const float* wp; int K, rel;
        if (u < W3OFF)      { wp = w2; K = 64;  rel = u; }
        else if (u < W4OFF) { wp = w3; K = 128; rel = u - W3OFF; }
        else if (u < W5OFF) { wp = w4; K = 192; rel = u - W4OFF; }
        else                { wp = w5; K = 256; rel = u - W5OFF; }
        const int arow = (rel >> 2) & 63;
        const int s = rel >> 8;
        const float* p = &wp[arow * K + s * 32 + lq * 8];
#pragma unroll
        for (int e = 0; e < 8; ++e) src[e] = p[e];
    } else {
        const int rel = u - W6OFF;        // (c*16 + r)*4 + lq, c in 0..11
        const int r = (rel >> 2) & 15;
        const int c = rel >> 6;
        if (r < 4 && c < 10) {
            const float* p = &w6[r * 320 + c * 32 + lq * 8];
#pragma unroll
            for (int e = 0; e < 8; ++e) src[e] = p[e];
        } else {
#pragma unroll
            for (int e = 0; e < 8; ++e) src[e] = 0.0f;   // pad rows/chunks
        }
    }
    uint4v o;
    o[0] = pk2(src[0], src[1]); o[1] = pk2(src[2], src[3]);
    o[2] = pk2(src[4], src[5]); o[3] = pk2(src[6], src[7]);
    ws[u] = __builtin_bit_cast(ushort8, o);
}

// one dense layer: reads X[0..K), writes relu(W X + b) into X[K..K+64).
// A-fragments streamed from ws (L2-resident), transient registers only.
template <int NCH>  // K = NCH*32 input channels
__device__ __forceinline__ void dense_layer(const ushort8* __restrict__ wsL,
                                            const float* __restrict__ bL,
                                            unsigned short* Xs, int w, int lo16, int lq) {
    const int K = NCH * 32;
    const int arow = w * 16 + lo16;
    ushort8 af[NCH];
#pragma unroll
    for (int s = 0; s < NCH; ++s) af[s] = wsL[(s * 64 + arow) * 4 + lq];
    const float4v biasv = *(const float4v*)&bL[w * 16 + lq * 4];
#pragma unroll
    for (int pp = 0; pp < 2; ++pp) {
        const int px0 = (pp * 2) * 16 + lo16;
        const int px1 = (pp * 2 + 1) * 16 + lo16;
        float4v acc0 = biasv, acc1 = biasv;
#pragma unroll
        for (int s = 0; s < NCH; ++s) {
            const bf16x8 bf0 = __builtin_bit_cast(bf16x8, *(const ushort8*)&Xs[(s * 4 + lq) * 512 + px0 * 8]);
            const bf16x8 bf1 = __builtin_bit_cast(bf16x8, *(const ushort8*)&Xs[(s * 4 + lq) * 512 + px1 * 8]);
            const bf16x8 afv = __builtin_bit_cast(bf16x8, af[s]);
            acc0 = __builtin_amdgcn_mfma_f32_16x16x32_bf16(afv, bf0, acc0, 0, 0, 0);
            acc1 = __builtin_amdgcn_mfma_f32_16x16x32_bf16(afv, bf1, acc1, 0, 0, 0);
        }
        const int cb = K + w * 16 + lq * 4;
        uint2v o0, o1;
        o0[0] = pk2(fmaxf(acc0[0], 0.0f), fmaxf(acc0[1], 0.0f));
        o0[1] = pk2(fmaxf(acc0[2], 0.0f), fmaxf(acc0[3], 0.0f));
        o1[0] = pk2(fmaxf(acc1[0], 0.0f), fmaxf(acc1[1], 0.0f));
        o1[1] = pk2(fmaxf(acc1[2], 0.0f), fmaxf(acc1[3], 0.0f));
        *(uint2v*)&Xs[(cb >> 3) * 512 + px0 * 8 + (cb & 7)] = o0;
        *(uint2v*)&Xs[(cb >> 3) * 512 + px1 * 8 + (cb & 7)] = o1;
    }
    __syncthreads();
}

__global__
__attribute__((amdgpu_flat_work_group_size(256, 256)))
__attribute__((amdgpu_waves_per_eu(4, 4)))
void bnet_mlp_kernel(
    const float* __restrict__ x,
    const float* __restrict__ wx, const float* __restrict__ bx,
    const float* __restrict__ wcs, const float* __restrict__ bcs,
    const float* __restrict__ wc, const float* __restrict__ bc,
    const float* __restrict__ b2, const float* __restrict__ b3,
    const float* __restrict__ b4, const float* __restrict__ b5,
    const ushort8* __restrict__ wsb,
    float* __restrict__ par)  // par[ch][b][pix], ch-major; pre-zeroed
{
    __shared__ unsigned short Xs[20480];    // 40 chunks x 1024 B = 40 KB exactly
    float* red = (float*)Xs;                // 4 KB aliased into chunks 0-3 (dead at flush)

    const int t = threadIdx.x;
    const int lane = t & 63;
    const int lo16 = lane & 15;
    const int lq = lane >> 4;
    const int w = __builtin_amdgcn_readfirstlane(t >> 6);  // wave id 0..3 = o-tile

    // ---- item chunk: 9600 items over 1024 blocks -> 384 x10 + 640 x9 ----
    const int bid = blockIdx.x;
    const int nit = 9 + (bid < 384 ? 1 : 0);
    const int g0  = (bid < 384) ? bid * 10 : bid * 9 + 384;

    // w6 partial accumulator: persists across all variants of the same (tile,b)
    float4v acc6[4];
    int cur_tb = -1;

    for (int it = 0; it < nit; ++it) {
        const int g = g0 + it;            // g = (tile*2+b)*12 + (mode*4+k)
        const int v = g % 12;
        const int tb = g / 12;
        const int tile = tb >> 1;
        const int b = tb & 1;
        const int mode = v >> 2;          // 0='x', 1='s', 2='c'
        const int k = v & 3;              // rotation

        __syncthreads();  // prior item's w6 reads of Xs done; Xs/red reusable

        if (tb != cur_tb) {               // block-uniform condition
            if (cur_tb >= 0) {
                // ---- flush prev tb: reduce partials across waves, 1 atomic set ----
                const int ftile = cur_tb >> 1;
                const int fb = cur_tb & 1;
                if (lq == 0) {
#pragma unroll
                    for (int pt = 0; pt < 4; ++pt)
                        *(float4v*)&red[(((w * 4) + pt) * 16 + lo16) * 4] = acc6[pt];
                }
                __syncthreads();
                if (w == 0) {
                    float4v sv;
#pragma unroll
                    for (int r = 0; r < 4; ++r)
                        sv[r] = red[(((0 * 4) + lq) * 16 + lo16) * 4 + r]
                              + red[(((1 * 4) + lq) * 16 + lo16) * 4 + r]
                              + red[(((2 * 4) + lq) * 16 + lo16) * 4 + r]
                              + red[(((3 * 4) + lq) * 16 + lo16) * 4 + r];
                    const int pixg = ftile * 64 + lq * 16 + lo16;
#pragma unroll
                    for (int r = 0; r < 4; ++r)
                        atomicAdd(&par[(r * 2 + fb) * NPIX + pixg], sv[r]);  // b6 folded into kernel 2
                }
                __syncthreads();  // wave 0 done with red before conv overwrites chunks 0-3
            }
#pragma unroll
            for (int pt = 0; pt < 4; ++pt) { float4v z = {0.f, 0.f, 0.f, 0.f}; acc6[pt] = z; }
            cur_tb = tb;
        }

        const float* xb = x + b * NPIX;
        const float* w1 = (mode == 0) ? wx : (mode == 1) ? wcs : wc;
        const float* b1 = (mode == 0) ? bx : (mode == 1) ? bcs : bc;
        int DY[4], DX[4];
        if (mode == 0)      { DY[0]=0; DY[1]=0; DY[2]=1; DY[3]=1;  DX[0]=0; DX[1]=1; DX[2]=0; DX[3]=1; }
        else if (mode == 1) { DY[0]=0; DY[1]=1; DY[2]=1; DY[3]=2;  DX[0]=0; DX[1]=1; DX[2]=2; DX[3]=1; }
        else                { DY[0]=0; DY[1]=0; DY[2]=2; DY[3]=2;  DX[0]=0; DX[1]=2; DX[2]=0; DX[3]=2; }

        const int pix = tile * 64 + lane;
        const int pi = pix / NN;
        const int pj = pix - pi * NN;

        // ---- stage 1: 4-tap conv; thread owns ch w*16..+15 at px=lane ----
        float s4[4];
#pragma unroll
        for (int tt = 0; tt < 4; ++tt) {
            const int dy = DY[tt], dx = DX[tt];
            int r, c;
            if (k == 0)      { r = refp(pi + dy); c = refp(pj + dx); }
            else if (k == 1) { r = refp(pi + dx); c = (pj >= dy) ? (pj - dy) : (dy - pj); }
            else if (k == 2) { r = (pi >= dy) ? (pi - dy) : (dy - pi);
                               c = (pj >= dx) ? (pj - dx) : (dx - pj); }
            else             { r = (pi >= dx) ? (pi - dx) : (dx - pi); c = refp(pj + dy); }
            s4[tt] = xb[r * NN + c];
        }
        float4v b1v[4];
#pragma unroll
        for (int q = 0; q < 4; ++q) b1v[q] = *(const float4v*)&b1[w * 16 + q * 4];
        float co[16];
#pragma unroll
        for (int oo = 0; oo < 16; ++oo) {
            const int o = w * 16 + oo;
            const float4v wv = *(const float4v*)&w1[o * 4];
            float cacc = b1v[oo >> 2][oo & 3];
#pragma unroll
            for (int tt = 0; tt < 4; ++tt) cacc = fmaf(wv[tt], s4[tt], cacc);
            co[oo] = fmaxf(cacc, 0.0f);
        }
        uint4v pka, pkb;
#pragma unroll
        for (int q = 0; q < 4; ++q) {
            pka[q] = pk2(co[2 * q], co[2 * q + 1]);
            pkb[q] = pk2(co[8 + 2 * q], co[9 + 2 * q]);
        }
        *(uint4v*)&Xs[(w * 2) * 512 + lane * 8]     = pka;
        *(uint4v*)&Xs[(w * 2 + 1) * 512 + lane * 8] = pkb;
        __syncthreads();

        dense_layer<2>(wsb + W2OFF, b2, Xs, w, lo16, lq);
        dense_layer<4>(wsb + W3OFF, b3, Xs, w, lo16, lq);
        dense_layer<6>(wsb + W4OFF, b4, Xs, w, lo16, lq);
        dense_layer<8>(wsb + W5OFF, b5, Xs, w, lo16, lq);

        // ---- final layer partials: wave w covers K-chunks 3w..3w+2 ----
        // a6 frags streamed from ws (pad chunks/rows are zeros)
        ushort8 a6[3];
#pragma unroll
        for (int c = 0; c < 3; ++c)
            a6[c] = wsb[W6OFF + ((3 * w + c) * 16 + lo16) * 4 + lq];
#pragma unroll
        for (int pt = 0; pt < 4; ++pt) {
            const int px = pt * 16 + lo16;
#pragma unroll
            for (int c = 0; c < 3; ++c) {
                int chb = (3 * w + c) * 32;
                chb = (chb < 288) ? chb : 288;   // clamp: A is zero there anyway
                const int c8 = (chb >> 3) + lq;
                const bf16x8 bf = __builtin_bit_cast(
                    bf16x8, *(const ushort8*)&Xs[c8 * 512 + px * 8]);
                acc6[pt] = __builtin_amdgcn_mfma_f32_16x16x32_bf16(
                    __builtin_bit_cast(bf16x8, a6[c]), bf, acc6[pt], 0, 0, 0);
            }
        }
        // loop-top __syncthreads() protects Xs reuse across items
    }

    // ---- final flush of the last tb ----
    __syncthreads();   // all w6 reads of Xs complete before red aliases it
    {
        const int ftile = cur_tb >> 1;
        const int fb = cur_tb & 1;
        if (lq == 0) {
#pragma unroll
            for (int pt = 0; pt < 4; ++pt)
                *(float4v*)&red[(((w * 4) + pt) * 16 + lo16) * 4] = acc6[pt];
        }
        __syncthreads();
        if (w == 0) {
            float4v sv;
#pragma unroll
            for (int r = 0; r < 4; ++r)
                sv[r] = red[(((0 * 4) + lq) * 16 + lo16) * 4 + r]
                      + red[(((1 * 4) + lq) * 16 + lo16) * 4 + r]
                      + red[(((2 * 4) + lq) * 16 + lo16) * 4 + r]
                      + red[(((3 * 4) + lq) * 16 + lo16) * 4 + r];
            const int pixg = ftile * 64 + lq * 16 + lo16;
#pragma unroll
            for (int r = 0; r < 4; ++r)
                atomicAdd(&par[(r * 2 + fb) * NPIX + pixg], sv[r]);  // b6 folded into kernel 2
        }
    }
}

__global__ __launch_bounds__(64) void bnet_bilateral_kernel(
    const float* __restrict__ x, const float* __restrict__ b6,
    float* __restrict__ out)
{
    const int tid = blockIdx.x * 64 + threadIdx.x;  // 800 blocks x 64 = 51200 exactly
    const int b = tid / NPIX;
    const int pix = tid - b * NPIX;
    const int pi = pix / NN;
    const int pj = pix - pi * NN;

    float* par = out + 2 * NPIX;
    const float inv12 = 1.0f / 12.0f;
    const float p0 = par[(0 + b) * NPIX + pix] * inv12 + b6[0];
    const float p1 = par[(2 + b) * NPIX + pix] * inv12 + b6[1];
    const float p2 = par[(4 + b) * NPIX + pix] * inv12 + b6[2];
    const float p3 = par[(6 + b) * NPIX + pix] * inv12 + b6[3];

    float sigx = 1.0f / (1.0f + __expf(-p0)) + 1e-6f;
    sigx = fminf(fmaxf(sigx, 0.0f), 1.0f);
    float sigy = 1.0f / (1.0f + __expf(-p1)) + 1e-6f;
    sigy = fminf(fmaxf(sigy, 0.0f), 1.0f);
    float t2 = __expf(2.0f * fminf(fmaxf(p2, -15.0f), 15.0f));
    float th = (t2 - 1.0f) / (t2 + 1.0f);
    th = fminf(fmaxf(th, -1.0f), 1.0f);
    float t3 = __expf(2.0f * fminf(fmaxf(p3, -15.0f), 15.0f));
    float sigr = (t3 - 1.0f) / (t3 + 1.0f) + 1e-6f;
    sigr = fminf(fmaxf(sigr, -1.0f), 1.0f);

    par[(0 + b) * NPIX + pix] = sigx;
    par[(2 + b) * NPIX + pix] = sigy;
    par[(4 + b) * NPIX + pix] = th;
    par[(6 + b) * NPIX + pix] = sigr;

    const float sx = sigx * 20.0f;
    const float sy = sigy * 20.0f;
    const float sr = sigr * 10.0f + 10.0f;

    const float* xb = x + b * NPIX;
    float patch[5][5];
#pragma unroll
    for (int ky = 0; ky < 5; ++ky) {
#pragma unroll
        for (int kx = 0; kx < 5; ++kx) {
            const int r = pi + ky - 2, c = pj + kx - 2;
            patch[ky][kx] = (r >= 0 && r < NN && c >= 0 && c < NN) ? xb[r * NN + c] : 0.0f;
        }
    }

    const float inv2sr2 = 1.0f / (2.0f * sr * sr);
    float num = 0.0f, den = 0.0f;
#pragma unroll
    for (int ky = 0; ky < 5; ++ky) {
#pragma unroll
        for (int kx = 0; kx < 5; ++kx) {
            const float v = patch[ky][kx];
            const float dxv = fabsf(patch[2][kx] - v);
            const float dyv = fabsf(patch[ky][2] - v);
            const float a = sx * dxv;
            const float bb = sy * dyv;
            const float sq = (float)((ky - 2) * (ky - 2) + (kx - 2) * (kx - 2));
            const float kern = __expf(-sq * inv2sr2 - 0.5f * (a * a - 2.0f * th * a * bb + bb * bb));
            den += kern;
            num = fmaf(kern, v, num);
        }
    }
    out[tid] = num / den;
}

extern "C" void kernel_launch(void* const* d_in, const int* in_sizes, int n_in,
                              void* d_out, int out_size, void* d_ws, size_t ws_size,
                              hipStream_t stream) {
    const float* x   = (const float*)d_in[0];
    const float* wx  = (const float*)d_in[1];
    const float* bx  = (const float*)d_in[2];
    const float* wc  = (const float*)d_in[3];
    const float* bc  = (const float*)d_in[4];
    const float* wcs = (const float*)d_in[5];
    const float* bcs = (const float*)d_in[6];
    const float* w2  = (const float*)d_in[7];
    const float* b2  = (const float*)d_in[8];
    const float* w3  = (const float*)d_in[9];
    const float* b3  = (const float*)d_in[10];
    const float* w4  = (const float*)d_in[11];
    const float* b4  = (const float*)d_in[12];
    const float* w5  = (const float*)d_in[13];
    const float* b5  = (const float*)d_in[14];
    const float* w6  = (const float*)d_in[15];
    const float* b6  = (const float*)d_in[16];
    float* out = (float*)d_out;
    ushort8* ws = (ushort8*)d_ws;

    // zero the par accumulator region (d_out tail, re-poisoned each launch)
    (void)hipMemsetAsync(out + 2 * NPIX, 0, 8 * NPIX * sizeof(float), stream);

    // convert weights fp32 -> bf16 fragments into workspace (L2-resident)
    hipLaunchKernelGGL(bnet_prep_kernel, dim3(WSUNITS / 256), dim3(256), 0, stream,
                       w2, w3, w4, w5, w6, ws);

    hipLaunchKernelGGL(bnet_mlp_kernel, dim3(1024), dim3(256), 0, stream,
                       x, wx, bx, wcs, bcs, wc, bc,
                       b2, b3, b4, b5, (const ushort8*)ws,
                       out + 2 * NPIX);

    hipLaunchKernelGGL(bnet_bilateral_kernel, dim3(800), dim3(64), 0, stream,
                       x, b6, out);
}